// Round 1
// 197.109 us; speedup vs baseline: 1.0249x; 1.0249x over previous
//
#include <hip/hip_runtime.h>

#define N_TOK  8192
#define KDIM   4096
#define NE     16
#define NSLICE 8                   // ws partials per token (one per k-octant block)
#define TB     64                  // tokens per block (= wave width)

// R7: drop the global_load_lds staging pipeline entirely.
// R6 counters (90us, VALUBusy 8%, ~775 GB/s) show the tile pipeline is
// latency/serialization-bound: vmcnt(0)+__syncthreads per 32KB tile with only
// 2 blocks/CU (64KB LDS each) leaves the CU idle ~2-3k cycles per tile.
// The LDS round-trip only existed to coalesce x for the lane=token layout.
// Direct per-lane float4 streaming gets the same DRAM-line utilization:
// each lane consumes its 64B lines fully via 4 consecutive 16B loads
// (temporal reuse in L1/L2), k stays wave-uniform so gate rows remain free
// scalar s_loads, and there are NO barriers / NO vmcnt drains in the k-loop.
// 32 strips x 128k (512B each) statically cover every 512B sub-offset of the
// 16KB row period -> uniform HBM channel load (what R6's rotation emulated).
// Occupancy: 17KB LDS + ~64 VGPR -> 4 blocks/CU = 16 waves/CU (was 8).
// Prediction: partial ~25-35us, VALUBusy 30-50%, total ~145-160us.
__global__ __launch_bounds__(256, 4)
void router_partial(const float* __restrict__ x, const float* __restrict__ gate,
                    float* __restrict__ ws) {
  __shared__ float red[256 * 17];            // cross-wave reduction only
  const int tid  = threadIdx.x;
  const int lane = tid & 63;
  const int w    = __builtin_amdgcn_readfirstlane(tid >> 6);
  const int g    = blockIdx.x >> 3;          // token group (128)
  const int q    = blockIdx.x & 7;           // k-octant (8) -> ws slice
  const int t0   = g * TB;
  const int sid  = q * 4 + w;                // 32 strips of 128 k
  const int k0   = sid * 128;

  const float4* xr = (const float4*)(x + (size_t)(t0 + lane) * KDIM + k0);
  const float*  gb = gate + (size_t)k0 * NE; // wave-uniform -> scalar s_loads

  float acc[NE];
#pragma unroll
  for (int e = 0; e < NE; ++e) acc[e] = 0.f;

  // 32 float4 loads per lane, 2-deep register ping-pong (statically unrolled:
  // all indices compile-time -> stays in VGPRs, rule-#20 safe). Each chunk is
  // 4 consecutive 16B loads (one full 64B line per lane) issued one full
  // 256-FMA block ahead of use.
  float4 cur[4], nxt[4];
#pragma unroll
  for (int u = 0; u < 4; ++u) cur[u] = xr[u];
#pragma unroll
  for (int jc = 0; jc < 8; ++jc) {
    if (jc < 7) {
#pragma unroll
      for (int u = 0; u < 4; ++u) nxt[u] = xr[(jc + 1) * 4 + u];
    }
#pragma unroll
    for (int u = 0; u < 4; ++u) {
      const float xv[4] = {cur[u].x, cur[u].y, cur[u].z, cur[u].w};
#pragma unroll
      for (int m = 0; m < 4; ++m) {
        const float* grow = gb + (size_t)(jc * 16 + u * 4 + m) * NE; // uniform
#pragma unroll
        for (int e = 0; e < NE; ++e) acc[e] = fmaf(xv[m], grow[e], acc[e]);
      }
    }
#pragma unroll
    for (int u = 0; u < 4; ++u) cur[u] = nxt[u];
  }

  // cross-wave reduction (4 strips of 128k -> one 512k partial), then one
  // float4 per thread into ws[q]
#pragma unroll
  for (int e = 0; e < NE; ++e) red[(w * 64 + lane) * 17 + e] = acc[e];
  __syncthreads();
  {
    int p0 = tid * 4;                        // 1024 (token,e) pairs, 4/thread
    int t  = p0 >> 4, e0 = p0 & 15;
    float v[4];
#pragma unroll
    for (int j = 0; j < 4; ++j) {
      float sum = 0.f;
#pragma unroll
      for (int ww = 0; ww < 4; ++ww) sum += red[(ww * 64 + t) * 17 + e0 + j];
      v[j] = sum;
    }
    *(float4*)(ws + ((size_t)q * N_TOK + (t0 + t)) * NE + e0) =
        make_float4(v[0], v[1], v[2], v[3]);
  }
}

// Sum 8 slice partials, top-2 (earliest-index tie-break = jax top_k),
// sigmoid, scatter into (E,N) scores; token_indices[e][t] = t (as float).
__global__ __launch_bounds__(256)
void router_finalize(const float* __restrict__ ws, float* __restrict__ out) {
  int t = blockIdx.x * 256 + threadIdx.x;
  float l[NE];
#pragma unroll
  for (int e = 0; e < NE; ++e) l[e] = 0.f;
#pragma unroll
  for (int s = 0; s < NSLICE; ++s) {
    const float4* row = (const float4*)(ws + ((size_t)s * N_TOK + t) * NE);
    float4 r0 = row[0], r1 = row[1], r2 = row[2], r3 = row[3];
    l[0]  += r0.x; l[1]  += r0.y; l[2]  += r0.z; l[3]  += r0.w;
    l[4]  += r1.x; l[5]  += r1.y; l[6]  += r1.z; l[7]  += r1.w;
    l[8]  += r2.x; l[9]  += r2.y; l[10] += r2.z; l[11] += r2.w;
    l[12] += r3.x; l[13] += r3.y; l[14] += r3.z; l[15] += r3.w;
  }
  int i1 = 0; float v1 = l[0];
#pragma unroll
  for (int e = 1; e < NE; ++e) { if (l[e] > v1) { v1 = l[e]; i1 = e; } }
  int i2 = -1; float v2 = -1e30f;
#pragma unroll
  for (int e = 0; e < NE; ++e) { if (e != i1 && l[e] > v2) { v2 = l[e]; i2 = e; } }
  float s1 = 1.f / (1.f + __expf(-v1));
  float s2 = 1.f / (1.f + __expf(-v2));
  float* scores = out;
  float* tix    = out + (size_t)NE * N_TOK;
  float tf = (float)t;
#pragma unroll
  for (int e = 0; e < NE; ++e) {             // coalesced across lanes per e
    scores[(size_t)e * N_TOK + t] = (e == i1) ? s1 : ((e == i2) ? s2 : 0.f);
    tix[(size_t)e * N_TOK + t]    = tf;
  }
}

extern "C" void kernel_launch(void* const* d_in, const int* in_sizes, int n_in,
                              void* d_out, int out_size, void* d_ws, size_t ws_size,
                              hipStream_t stream) {
  const float* x    = (const float*)d_in[0];
  const float* gate = (const float*)d_in[1];
  float* out = (float*)d_out;
  float* ws  = (float*)d_ws;   // needs NSLICE*N_TOK*NE*4 = 4 MB
  router_partial<<<dim3(N_TOK / TB * NSLICE), dim3(256), 0, stream>>>(x, gate, ws);
  router_finalize<<<dim3(N_TOK / 256), dim3(256), 0, stream>>>(ws, out);
}